// Round 5
// baseline (290.205 us; speedup 1.0000x reference)
//
#include <hip/hip_runtime.h>

// GroupTokenizer: y [B,T,C] f32, edges [C,K] f32 -> labels [B,T,C] (as f32), reg [B,T,C,K] f32.
// B=32 T=4096 C=8 K=64. Output = 272.6 MB, 98.4% of which is the constant -1.0f.
// R4->R5: "fill + patch" restructure. Old version redistributed label/delta via 32
// ds_bpermute + 4 cmp/cndmask per float4 store (~2x the VALU budget 6.3 TB/s allows;
// measured ~2.9 TB/s effective). New version: bulk-store constant (-1)^4 dwordx4
// (zero per-store VALU, like the 6.4 TB/s rocclr fill), s_waitcnt vmcnt(0), then
// patch one 4B delta per element into the freshly L2-dirty tile.
#define N_ELEM (32 * 4096 * 8)
#define CCH 8
#define KB 64

typedef float vfloat4 __attribute__((ext_vector_type(4)));

__global__ __launch_bounds__(256) void group_tokenizer_kernel(
    const float* __restrict__ y,
    const float* __restrict__ le,
    const float* __restrict__ re,
    float* __restrict__ out,
    int ngroups) {
  // Edges in LDS, stride K+1=65: bank = (c + k) % 32, distinct across channels;
  // same-channel lanes read identical addresses -> broadcast (free).
  __shared__ float ls[CCH][KB + 1];
  __shared__ float rs[CCH][KB + 1];
  const int tid = threadIdx.x;
  for (int t = tid; t < CCH * KB; t += blockDim.x) {
    ls[t >> 6][t & 63] = le[t];
    rs[t >> 6][t & 63] = re[t];
  }
  __syncthreads();

  const int lane = tid & 63;
  const int wid = tid >> 6;
  const int g = blockIdx.x * 4 + wid;          // one 64-element tile per wave
  if (g >= ngroups) return;

  const int e = g * 64 + lane;                 // element index (lane-contiguous)
  const float yv = y[e];
  const int c = lane & (CCH - 1);              // e % 8 == lane % 8 (tile base % 64 == 0)
  const float* lr = ls[c];
  const float* rr = rs[c];

  // lower_bound on r: first k with yv < r[k]. 65 possible answers -> 7 branchless
  // steps (6 left a size-1 interval untested: round-2 absmax=2.0 bug).
  int lo = 0, hi = KB;
#pragma unroll
  for (int it = 0; it < 7; ++it) {
    const int mid = (lo + hi) >> 1;
    const bool cond = yv < rr[mid];
    hi = cond ? mid : hi;
    lo = cond ? lo : mid + 1;
  }
  // in_bin[lo] iff yv >= l[lo]; else no bin -> label K-1. (lo==KB read safe: padded.)
  const int label = (lo < KB && yv >= lr[lo]) ? lo : (KB - 1);

  const float left = lr[label];
  const float right = rr[label];
  const float width = fmaxf(right - left, 1e-12f);
  float delta = fminf(fmaxf((yv - left) / width, 0.0f), 1.0f);

  // labels output (as float), coalesced 256 B/wave.
  out[e] = (float)label;

  // Phase 1: bulk -1.0f fill of this wave's 16 KB reg tile. 16 dwordx4 stores,
  // fully coalesced (1 KB/instr), no data-dependent VALU in the loop.
  float* tile = out + (size_t)N_ELEM + (size_t)g * (64 * KB);
  const vfloat4 neg1 = {-1.0f, -1.0f, -1.0f, -1.0f};
  vfloat4* tv = (vfloat4*)tile + lane;
#pragma unroll
  for (int j = 0; j < 16; ++j) {
    tv[j * 64] = neg1;
  }

  // Drain fills to L2 so the patch below (same addresses) lands after them.
  __builtin_amdgcn_s_waitcnt(0x0F70);  // vmcnt(0), lgkmcnt/expcnt untouched

  // Phase 2: patch the single informative dword per element. 64 scattered 4B
  // stores per wave into lines this wave just made L2-dirty -> no HBM RMW.
  tile[lane * KB + label] = delta;
}

extern "C" void kernel_launch(void* const* d_in, const int* in_sizes, int n_in,
                              void* d_out, int out_size, void* d_ws, size_t ws_size,
                              hipStream_t stream) {
  const float* y = (const float*)d_in[0];
  const float* le = (const float*)d_in[1];
  const float* re = (const float*)d_in[2];
  float* out = (float*)d_out;

  const int n = in_sizes[0];          // 1048576
  const int ngroups = n / 64;         // 16384 wave-tiles
  const int blocks = (ngroups + 3) / 4;  // 4 waves (tiles) per 256-thread block

  group_tokenizer_kernel<<<blocks, 256, 0, stream>>>(y, le, re, out, ngroups);
}

// Round 6
// 277.022 us; speedup vs baseline: 1.0476x; 1.0476x over previous
//
#include <hip/hip_runtime.h>

// GroupTokenizer: y [B,T,C] f32, edges [C,K] f32 -> labels [B,T,C] (as f32), reg [B,T,C,K] f32.
// B=32 T=4096 C=8 K=64. Output = 272.6 MB streaming stores.
// History: R4 (shuffle single-pass) and R5 (fill+patch) both land at dur_us - poisonfill
// ~= 93-103 us; VALU arithmetic says both should be HBM-bound at ~45 us. R6 tests the
// remaining kernel-side hypothesis: 1-tile-per-wave = shallow pipelining (per-tile
// prologue of ~1700 serial cycles, then exit). Now: grid-stride, 4 tiles/wave,
// single-pass full-line stores (no patch: partial-line RMW risk after L2 eviction).
#define N_ELEM (32 * 4096 * 8)
#define CCH 8
#define KB 64

typedef float vfloat4 __attribute__((ext_vector_type(4)));

__global__ __launch_bounds__(256) void group_tokenizer_kernel(
    const float* __restrict__ y,
    const float* __restrict__ le,
    const float* __restrict__ re,
    float* __restrict__ out,
    int ngroups) {
  // Edges in LDS, stride K+1=65: bank = (c + k) % 32, distinct across channels;
  // same-channel lanes read identical addresses -> broadcast (free).
  __shared__ float ls[CCH][KB + 1];
  __shared__ float rs[CCH][KB + 1];
  const int tid = threadIdx.x;
  for (int t = tid; t < CCH * KB; t += blockDim.x) {
    ls[t >> 6][t & 63] = le[t];
    rs[t >> 6][t & 63] = re[t];
  }
  __syncthreads();

  const int lane = tid & 63;
  const int wid = tid >> 6;
  const int gwave = blockIdx.x * 4 + wid;
  const int nwaves = gridDim.x * 4;

  // Loop-invariant hoists.
  const int c = lane & (CCH - 1);          // e % 8 == lane % 8 (tile base % 64 == 0)
  const float* lr = ls[c];
  const float* rr = rs[c];
  const int kst = (lane & 15) << 2;        // this lane's k-offset within its element
  const int src_base = lane >> 4;

  for (int g = gwave; g < ngroups; g += nwaves) {
    const float yv = y[g * 64 + lane];

    // lower_bound on r: first k with yv < r[k]. 65 possible answers -> 7 branchless
    // steps (6 left a size-1 interval untested: round-2 absmax=2.0 bug).
    int lo = 0, hi = KB;
#pragma unroll
    for (int it = 0; it < 7; ++it) {
      const int mid = (lo + hi) >> 1;
      const bool cond = yv < rr[mid];
      hi = cond ? mid : hi;
      lo = cond ? lo : mid + 1;
    }
    // in_bin[lo] iff yv >= l[lo]; else no bin -> label K-1. (lo==KB read safe: padded.)
    const int label = (lo < KB && yv >= lr[lo]) ? lo : (KB - 1);

    const float left = lr[label];
    const float width = fmaxf(rr[label] - left, 1e-12f);
    const float delta = fminf(fmaxf((yv - left) / width, 0.0f), 1.0f);

    // labels output (as float), 256 B/wave coalesced full lines.
    out[g * 64 + lane] = (float)label;

    // reg tile: 64 elems * 64 bins = 16 KB contiguous per wave-iteration.
    // 16 fully-coalesced dwordx4 stores (1 KB/instr, every 128 B line fully covered
    // by one instruction -> zero write-allocate fetches).
    vfloat4* regv = (vfloat4*)(out + (size_t)N_ELEM + (size_t)g * (64 * KB)) + lane;
#pragma unroll
    for (int j = 0; j < 16; ++j) {
      const int src = (j << 2) + src_base;      // which lane's element this float4 belongs to
      const int lbl = __shfl(label, src, 64);
      const float dlt = __shfl(delta, src, 64);
      vfloat4 v;
      v.x = (kst + 0 == lbl) ? dlt : -1.0f;
      v.y = (kst + 1 == lbl) ? dlt : -1.0f;
      v.z = (kst + 2 == lbl) ? dlt : -1.0f;
      v.w = (kst + 3 == lbl) ? dlt : -1.0f;
      regv[j << 6] = v;
    }
    // No wait here: next iteration's y-load/search overlaps this tile's store drain.
  }
}

extern "C" void kernel_launch(void* const* d_in, const int* in_sizes, int n_in,
                              void* d_out, int out_size, void* d_ws, size_t ws_size,
                              hipStream_t stream) {
  const float* y = (const float*)d_in[0];
  const float* le = (const float*)d_in[1];
  const float* re = (const float*)d_in[2];
  float* out = (float*)d_out;

  const int n = in_sizes[0];          // 1048576
  const int ngroups = n / 64;         // 16384 wave-tiles
  const int blocks = 1024;            // 4096 waves, 4 tiles per wave (grid-stride)

  group_tokenizer_kernel<<<blocks, 256, 0, stream>>>(y, le, re, out, ngroups);
}